// Round 1
// baseline (364.504 us; speedup 1.0000x reference)
//
#include <hip/hip_runtime.h>
#include <math.h>

#define TT 2048
#define CDIM 1024
#define KAUG 1088
#define BT 4096

typedef __attribute__((ext_vector_type(8))) short bf16x8;
typedef __attribute__((ext_vector_type(4))) short short4v;
typedef __attribute__((ext_vector_type(4))) float f32x4;

static __device__ __forceinline__ float bf2f(short s) {
  union { unsigned int u; float f; } c;
  c.u = ((unsigned int)(unsigned short)s) << 16;
  return c.f;
}
static __device__ __forceinline__ short f2bf(float f) {
  union { float f; unsigned int u; } c; c.f = f;
  unsigned int u = c.u;
  u += 0x7fff + ((u >> 16) & 1);   // round-to-nearest-even
  return (short)(u >> 16);
}

static __device__ __forceinline__ void gload_lds16(const void* g, void* l) {
  __builtin_amdgcn_global_load_lds(
      (const __attribute__((address_space(1))) void*)g,
      (__attribute__((address_space(3))) void*)l, 16, 0, 0);
}

// ---------------------------------------------------------------------------
// rank1: xa = x @ A_attn^T (fp32), fused with packing x -> Xaug (bf16) and
// writing cols [1024,1040) = 2*xa (bf16), [1040,1088) = 0.
// One block = 16 rows.
__global__ __launch_bounds__(256) void rank1_kernel(
    const float* __restrict__ x, const float* __restrict__ Aattn,
    short* __restrict__ Xaug) {
  __shared__ float xls[16][1024];
  const int tid = threadIdx.x;
  const int row0 = blockIdx.x * 16;
  for (int i = tid; i < 16 * 256; i += 256) {
    int row = i >> 8, c4 = (i & 255) * 4;
    float4 v = *(const float4*)(x + (size_t)(row0 + row) * CDIM + c4);
    *(float4*)&xls[row][c4] = v;
    short4v p;
    p.x = f2bf(v.x); p.y = f2bf(v.y); p.z = f2bf(v.z); p.w = f2bf(v.w);
    *(short4v*)(Xaug + (size_t)(row0 + row) * KAUG + c4) = p;
  }
  __syncthreads();
  const int row = tid >> 4, r = tid & 15;
  float acc = 0.f;
  for (int c = 0; c < 1024; c += 4) {
    float4 a = *(const float4*)(Aattn + (size_t)r * 1024 + c);
    float4 xv = *(const float4*)&xls[row][c];
    acc += a.x * xv.x + a.y * xv.y + a.z * xv.z + a.w * xv.w;
  }
  Xaug[(size_t)(row0 + row) * KAUG + 1024 + r] = f2bf(2.f * acc);
  for (int i = tid; i < 16 * 48; i += 256) {
    int rr = i / 48, cc = 1040 + (i % 48);
    Xaug[(size_t)(row0 + rr) * KAUG + cc] = 0;
  }
}

// ---------------------------------------------------------------------------
// rank2: ca = ctx @ A_proj^T where ctx = Caug cols [0,1024) (bf16, stride KAUG);
// writes Caug cols [1024,1040) = 2*ca (bf16), [1040,1088) = 0.
__global__ __launch_bounds__(256) void rank2_kernel(
    const float* __restrict__ Aproj, short* __restrict__ Caug) {
  __shared__ float cls[16][1024];
  const int tid = threadIdx.x;
  const int row0 = blockIdx.x * 16;
  for (int i = tid; i < 16 * 128; i += 256) {
    int row = i >> 7, c8 = (i & 127) * 8;
    bf16x8 v = *(const bf16x8*)(Caug + (size_t)(row0 + row) * KAUG + c8);
#pragma unroll
    for (int j = 0; j < 8; j++) cls[row][c8 + j] = bf2f(v[j]);
  }
  __syncthreads();
  const int row = tid >> 4, r = tid & 15;
  float acc = 0.f;
  for (int c = 0; c < 1024; c += 4) {
    float4 a = *(const float4*)(Aproj + (size_t)r * 1024 + c);
    float4 xv = *(const float4*)&cls[row][c];
    acc += a.x * xv.x + a.y * xv.y + a.z * xv.z + a.w * xv.w;
  }
  Caug[(size_t)(row0 + row) * KAUG + 1024 + r] = f2bf(2.f * acc);
  for (int i = tid; i < 16 * 48; i += 256) {
    int rr = i / 48, cc = 1040 + (i % 48);
    Caug[(size_t)(row0 + rr) * KAUG + cc] = 0;
  }
}

// ---------------------------------------------------------------------------
// pack W (fp32 [rows][1024]) + Bmat (fp32 [rows][16]) -> Waug bf16 [rows][1088]
__global__ __launch_bounds__(256) void packw_kernel(
    const float* __restrict__ W, const float* __restrict__ Bm,
    short* __restrict__ Waug, int rows) {
  int i = blockIdx.x * 256 + threadIdx.x;
  int total = rows * 136;
  if (i >= total) return;
  int row = i / 136;
  int c8 = (i - row * 136) * 8;
  bf16x8 p;
  if (c8 < 1024) {
    float4 v0 = *(const float4*)(W + (size_t)row * 1024 + c8);
    float4 v1 = *(const float4*)(W + (size_t)row * 1024 + c8 + 4);
    p[0] = f2bf(v0.x); p[1] = f2bf(v0.y); p[2] = f2bf(v0.z); p[3] = f2bf(v0.w);
    p[4] = f2bf(v1.x); p[5] = f2bf(v1.y); p[6] = f2bf(v1.z); p[7] = f2bf(v1.w);
  } else if (c8 < 1040) {
#pragma unroll
    for (int j = 0; j < 8; j++) p[j] = f2bf(Bm[(size_t)row * 16 + (c8 - 1024) + j]);
  } else {
#pragma unroll
    for (int j = 0; j < 8; j++) p[j] = 0;
  }
  *(bf16x8*)(Waug + (size_t)row * KAUG + c8) = p;
}

// ---------------------------------------------------------------------------
// 128x128 bf16 MFMA GEMM, K = KAUG. A [M][KAUG], B [N][KAUG] (both K-major).
// EPI 0: QKV epilogue (bias, q-scale, fake-quant K/V, [B,H,T,HD] layout)
// EPI 1: proj epilogue (bias, fp32 out)
template <int EPI>
__global__ __launch_bounds__(256) void gemm_kernel(
    const short* __restrict__ Amat, const short* __restrict__ Bmat,
    const float* __restrict__ bias,
    const float* __restrict__ kv_scale, const float* __restrict__ kv_zp,
    short* __restrict__ Qb, short* __restrict__ Kb, short* __restrict__ Vb,
    float* __restrict__ Out) {
  __shared__ short Als[128 * 64];
  __shared__ short Bls[128 * 64];
  const int tid = threadIdx.x;
  const int lane = tid & 63;
  const int wid = tid >> 6;
  const int wr = wid >> 1, wc = wid & 1;
  const int r16 = lane & 15, g = lane >> 4;
  const int bm = blockIdx.x * 128;
  const int bn = blockIdx.y * 128;

  f32x4 zero = {0.f, 0.f, 0.f, 0.f};
  f32x4 acc[4][4];
#pragma unroll
  for (int i = 0; i < 4; i++)
#pragma unroll
    for (int j = 0; j < 4; j++) acc[i][j] = zero;

  for (int k0 = 0; k0 < KAUG; k0 += 64) {
    __syncthreads();
    // stage A/B tiles: LDS chunk (row, cs) holds global chunk (row, cs^(row&7))
#pragma unroll
    for (int i = 0; i < 4; i++) {
      int L = i * 256 + tid;
      int row = L >> 3, cs = L & 7;
      int cg = cs ^ (row & 7);
      gload_lds16(Amat + (size_t)(bm + row) * KAUG + k0 + cg * 8,
                  (char*)Als + (i * 256 + wid * 64) * 16);
      gload_lds16(Bmat + (size_t)(bn + row) * KAUG + k0 + cg * 8,
                  (char*)Bls + (i * 256 + wid * 64) * 16);
    }
    __syncthreads();
#pragma unroll
    for (int kk = 0; kk < 2; kk++) {
      bf16x8 a[4], b[4];
#pragma unroll
      for (int mi = 0; mi < 4; mi++) {
        int row = wr * 64 + mi * 16 + r16;
        int cs = (kk * 4 + g) ^ (row & 7);
        a[mi] = *(const bf16x8*)((const char*)Als + (row * 8 + cs) * 16);
      }
#pragma unroll
      for (int ni = 0; ni < 4; ni++) {
        int row = wc * 64 + ni * 16 + r16;
        int cs = (kk * 4 + g) ^ (row & 7);
        b[ni] = *(const bf16x8*)((const char*)Bls + (row * 8 + cs) * 16);
      }
#pragma unroll
      for (int mi = 0; mi < 4; mi++)
#pragma unroll
        for (int ni = 0; ni < 4; ni++)
          acc[mi][ni] = __builtin_amdgcn_mfma_f32_16x16x32_bf16(
              a[mi], b[ni], acc[mi][ni], 0, 0, 0);
    }
  }

  if (EPI == 0) {
    const float scale = kv_scale[0];
    const float zp = kv_zp[0];
    const int which = bn >> 10;  // uniform per block (128 | 1024)
#pragma unroll
    for (int mi = 0; mi < 4; mi++)
#pragma unroll
      for (int ni = 0; ni < 4; ni++)
#pragma unroll
        for (int r = 0; r < 4; r++) {
          int m = bm + wr * 64 + mi * 16 + g * 4 + r;
          int n = bn + wc * 64 + ni * 16 + r16;
          float val = acc[mi][ni][r] + bias[n];
          int hn = n & 1023;
          size_t off = (((size_t)(m >> 11) * 16 + (hn >> 6)) * TT + (m & 2047)) * 64 + (hn & 63);
          if (which == 0) {
            Qb[off] = f2bf(val * 0.125f);  // fold 1/sqrt(64)
          } else {
            float q = rintf(val / scale + zp);   // round-half-even like jnp.round
            q = fminf(fmaxf(q, 0.f), 255.f);
            float deq = (q - zp) * scale;
            if (which == 1) Kb[off] = f2bf(deq);
            else            Vb[off] = f2bf(deq);
          }
        }
  } else {
#pragma unroll
    for (int mi = 0; mi < 4; mi++)
#pragma unroll
      for (int ni = 0; ni < 4; ni++)
#pragma unroll
        for (int r = 0; r < 4; r++) {
          int m = bm + wr * 64 + mi * 16 + g * 4 + r;
          int n = bn + wc * 64 + ni * 16 + r16;
          Out[(size_t)m * CDIM + n] = acc[mi][ni][r] + bias[n];
        }
  }
}

// ---------------------------------------------------------------------------
// causal flash attention, bf16 MFMA 16x16x32.
// grid (T/64, B*H), 4 waves; wave handles 16 q rows; KVBLK=32.
// Writes ctx (bf16) into Caug cols [0,1024) at row stride KAUG.
__global__ __launch_bounds__(256) void attn_kernel(
    const short* __restrict__ Qb, const short* __restrict__ Kb,
    const short* __restrict__ Vb, short* __restrict__ Caug) {
  __shared__ short Kls[32 * 72];     // K tile [32 kv][64 d], rows padded to 72
  __shared__ short Vtls[64 * 40];    // V^T tile [64 d][32 kv], rows padded to 40
  __shared__ short Pls[4][16 * 40];  // per-wave P [16 q][32 kv], rows padded to 40
  const int tid = threadIdx.x;
  const int lane = tid & 63;
  const int w = tid >> 6;
  const int r16 = lane & 15, g = lane >> 4;
  const int bh = blockIdx.y;
  const int q0 = blockIdx.x * 64;
  const size_t kvbase = (size_t)bh * TT * 64;

  bf16x8 qf[2];
  {
    const short* qp = Qb + kvbase + (size_t)(q0 + w * 16 + r16) * 64 + g * 8;
    qf[0] = *(const bf16x8*)(qp);
    qf[1] = *(const bf16x8*)(qp + 32);
  }
  f32x4 zero = {0.f, 0.f, 0.f, 0.f};
  f32x4 acc_o[4];
#pragma unroll
  for (int i = 0; i < 4; i++) acc_o[i] = zero;
  float m_run[4], l_run[4];
#pragma unroll
  for (int r = 0; r < 4; r++) { m_run[r] = -1e30f; l_run[r] = 0.f; }

  const int srow = tid >> 3;       // 0..31
  const int sc8 = (tid & 7) * 8;   // 0..56
  const int ntiles = (q0 + 64) >> 5;
  for (int kt = 0; kt < ntiles; kt++) {
    const int kv0 = kt * 32;
    {
      const size_t base = kvbase + (size_t)(kv0 + srow) * 64 + sc8;
      bf16x8 kvv = *(const bf16x8*)(Kb + base);
      *(bf16x8*)((char*)Kls + srow * 144 + sc8 * 2) = kvv;
      bf16x8 vvv = *(const bf16x8*)(Vb + base);
#pragma unroll
      for (int j = 0; j < 8; j++) Vtls[(sc8 + j) * 40 + srow] = vvv[j];
    }
    __syncthreads();

    f32x4 sc[2];
    sc[0] = zero; sc[1] = zero;
#pragma unroll
    for (int n2 = 0; n2 < 2; n2++)
#pragma unroll
      for (int kk = 0; kk < 2; kk++) {
        bf16x8 kf = *(const bf16x8*)((char*)Kls + (r16 + n2 * 16) * 144 + kk * 64 + g * 16);
        sc[n2] = __builtin_amdgcn_mfma_f32_16x16x32_bf16(qf[kk], kf, sc[n2], 0, 0, 0);
      }

#pragma unroll
    for (int r = 0; r < 4; r++) {
      const int qg = q0 + w * 16 + g * 4 + r;
      float s0 = sc[0][r], s1 = sc[1][r];
      if (kv0 + r16 > qg) s0 = -1e30f;
      if (kv0 + 16 + r16 > qg) s1 = -1e30f;
      float mx = fmaxf(s0, s1);
      mx = fmaxf(mx, __shfl_xor(mx, 1));
      mx = fmaxf(mx, __shfl_xor(mx, 2));
      mx = fmaxf(mx, __shfl_xor(mx, 4));
      mx = fmaxf(mx, __shfl_xor(mx, 8));
      float mnew = fmaxf(m_run[r], mx);
      float corr = __expf(m_run[r] - mnew);
      float p0 = __expf(s0 - mnew);
      float p1 = __expf(s1 - mnew);
      float ps = p0 + p1;
      ps += __shfl_xor(ps, 1);
      ps += __shfl_xor(ps, 2);
      ps += __shfl_xor(ps, 4);
      ps += __shfl_xor(ps, 8);
      l_run[r] = l_run[r] * corr + ps;
      m_run[r] = mnew;
      acc_o[0][r] *= corr; acc_o[1][r] *= corr;
      acc_o[2][r] *= corr; acc_o[3][r] *= corr;
      Pls[w][(g * 4 + r) * 40 + r16] = f2bf(p0);
      Pls[w][(g * 4 + r) * 40 + r16 + 16] = f2bf(p1);
    }
    asm volatile("s_waitcnt lgkmcnt(0)" ::: "memory");
    __builtin_amdgcn_sched_barrier(0);
    bf16x8 pf = *(const bf16x8*)((char*)&Pls[w][0] + r16 * 80 + g * 16);
#pragma unroll
    for (int dn = 0; dn < 4; dn++) {
      bf16x8 vf = *(const bf16x8*)((char*)Vtls + (r16 + dn * 16) * 80 + g * 16);
      acc_o[dn] = __builtin_amdgcn_mfma_f32_16x16x32_bf16(pf, vf, acc_o[dn], 0, 0, 0);
    }
    __syncthreads();
  }

  const int b = bh >> 4, h = bh & 15;
#pragma unroll
  for (int dn = 0; dn < 4; dn++)
#pragma unroll
    for (int r = 0; r < 4; r++) {
      int m = b * TT + q0 + w * 16 + g * 4 + r;
      int col = h * 64 + dn * 16 + r16;
      Caug[(size_t)m * KAUG + col] = f2bf(acc_o[dn][r] / l_run[r]);
    }
}

// ---------------------------------------------------------------------------
extern "C" void kernel_launch(void* const* d_in, const int* in_sizes, int n_in,
                              void* d_out, int out_size, void* d_ws, size_t ws_size,
                              hipStream_t stream) {
  const float* x       = (const float*)d_in[0];
  const float* W_attn  = (const float*)d_in[1];
  const float* b_attn  = (const float*)d_in[2];
  const float* A_attn  = (const float*)d_in[3];
  const float* B_attn  = (const float*)d_in[4];
  const float* W_proj  = (const float*)d_in[5];
  const float* b_proj  = (const float*)d_in[6];
  const float* A_proj  = (const float*)d_in[7];
  const float* B_proj  = (const float*)d_in[8];
  const float* kv_scale = (const float*)d_in[9];
  const float* kv_zp    = (const float*)d_in[10];
  float* out = (float*)d_out;

  char* p = (char*)d_ws;
  short* Xaug  = (short*)p; p += (size_t)BT * KAUG * 2;
  short* Waug1 = (short*)p; p += (size_t)3072 * KAUG * 2;
  short* Waug2 = (short*)p; p += (size_t)1024 * KAUG * 2;
  short* Caug  = (short*)p; p += (size_t)BT * KAUG * 2;
  short* Qb    = (short*)p; p += (size_t)32 * TT * 64 * 2;
  short* Kb    = (short*)p; p += (size_t)32 * TT * 64 * 2;
  short* Vb    = (short*)p; p += (size_t)32 * TT * 64 * 2;

  rank1_kernel<<<dim3(256), dim3(256), 0, stream>>>(x, A_attn, Xaug);
  packw_kernel<<<dim3(1632), dim3(256), 0, stream>>>(W_attn, B_attn, Waug1, 3072);
  packw_kernel<<<dim3(544), dim3(256), 0, stream>>>(W_proj, B_proj, Waug2, 1024);
  gemm_kernel<0><<<dim3(32, 24), dim3(256), 0, stream>>>(
      Xaug, Waug1, b_attn, kv_scale, kv_zp, Qb, Kb, Vb, (float*)nullptr);
  attn_kernel<<<dim3(32, 32), dim3(256), 0, stream>>>(Qb, Kb, Vb, Caug);
  rank2_kernel<<<dim3(256), dim3(256), 0, stream>>>(A_proj, Caug);
  gemm_kernel<1><<<dim3(32, 8), dim3(256), 0, stream>>>(
      Caug, Waug2, b_proj, kv_scale, kv_zp,
      (short*)nullptr, (short*)nullptr, (short*)nullptr, out);
}

// Round 2
// 232.237 us; speedup vs baseline: 1.5695x; 1.5695x over previous
//
#include <hip/hip_runtime.h>
#include <math.h>

#define TT 2048
#define CDIM 1024
#define KAUG 1088
#define BT 4096

typedef __attribute__((ext_vector_type(8))) short bf16x8;
typedef __attribute__((ext_vector_type(4))) short short4v;
typedef __attribute__((ext_vector_type(4))) float f32x4;
typedef __attribute__((ext_vector_type(16))) float f32x16;

static __device__ __forceinline__ float bf2f(short s) {
  union { unsigned int u; float f; } c;
  c.u = ((unsigned int)(unsigned short)s) << 16;
  return c.f;
}
static __device__ __forceinline__ short f2bf(float f) {
  union { float f; unsigned int u; } c; c.f = f;
  unsigned int u = c.u;
  u += 0x7fff + ((u >> 16) & 1);   // round-to-nearest-even
  return (short)(u >> 16);
}

static __device__ __forceinline__ void gload_lds16(const void* g, void* l) {
  __builtin_amdgcn_global_load_lds(
      (const __attribute__((address_space(1))) void*)g,
      (__attribute__((address_space(3))) void*)l, 16, 0, 0);
}

static __device__ __forceinline__ unsigned int cvt_pk_bf16(float lo, float hi) {
  unsigned int r;
  asm("v_cvt_pk_bf16_f32 %0, %1, %2" : "=v"(r) : "v"(lo), "v"(hi));
  return r;
}

// ---------------------------------------------------------------------------
// rank1: xa = x @ A_attn^T (fp32), fused with packing x -> Xaug (bf16) and
// writing cols [1024,1040) = 2*xa (bf16), [1040,1088) = 0.
__global__ __launch_bounds__(256) void rank1_kernel(
    const float* __restrict__ x, const float* __restrict__ Aattn,
    short* __restrict__ Xaug) {
  __shared__ float xls[16][1024];
  const int tid = threadIdx.x;
  const int row0 = blockIdx.x * 16;
  for (int i = tid; i < 16 * 256; i += 256) {
    int row = i >> 8, c4 = (i & 255) * 4;
    float4 v = *(const float4*)(x + (size_t)(row0 + row) * CDIM + c4);
    *(float4*)&xls[row][c4] = v;
    short4v p;
    p.x = f2bf(v.x); p.y = f2bf(v.y); p.z = f2bf(v.z); p.w = f2bf(v.w);
    *(short4v*)(Xaug + (size_t)(row0 + row) * KAUG + c4) = p;
  }
  __syncthreads();
  const int row = tid >> 4, r = tid & 15;
  float acc = 0.f;
  for (int c = 0; c < 1024; c += 4) {
    float4 a = *(const float4*)(Aattn + (size_t)r * 1024 + c);
    float4 xv = *(const float4*)&xls[row][c];
    acc += a.x * xv.x + a.y * xv.y + a.z * xv.z + a.w * xv.w;
  }
  Xaug[(size_t)(row0 + row) * KAUG + 1024 + r] = f2bf(2.f * acc);
  for (int i = tid; i < 16 * 48; i += 256) {
    int rr = i / 48, cc = 1040 + (i % 48);
    Xaug[(size_t)(row0 + rr) * KAUG + cc] = 0;
  }
}

// ---------------------------------------------------------------------------
// rank2: ca = ctx @ A_proj^T, ctx = Caug cols [0,1024) (bf16, stride KAUG);
// writes Caug cols [1024,1040) = 2*ca (bf16), [1040,1088) = 0.
__global__ __launch_bounds__(256) void rank2_kernel(
    const float* __restrict__ Aproj, short* __restrict__ Caug) {
  __shared__ float cls[16][1024];
  const int tid = threadIdx.x;
  const int row0 = blockIdx.x * 16;
  for (int i = tid; i < 16 * 128; i += 256) {
    int row = i >> 7, c8 = (i & 127) * 8;
    bf16x8 v = *(const bf16x8*)(Caug + (size_t)(row0 + row) * KAUG + c8);
#pragma unroll
    for (int j = 0; j < 8; j++) cls[row][c8 + j] = bf2f(v[j]);
  }
  __syncthreads();
  const int row = tid >> 4, r = tid & 15;
  float acc = 0.f;
  for (int c = 0; c < 1024; c += 4) {
    float4 a = *(const float4*)(Aproj + (size_t)r * 1024 + c);
    float4 xv = *(const float4*)&cls[row][c];
    acc += a.x * xv.x + a.y * xv.y + a.z * xv.z + a.w * xv.w;
  }
  Caug[(size_t)(row0 + row) * KAUG + 1024 + r] = f2bf(2.f * acc);
  for (int i = tid; i < 16 * 48; i += 256) {
    int rr = i / 48, cc = 1040 + (i % 48);
    Caug[(size_t)(row0 + rr) * KAUG + cc] = 0;
  }
}

// ---------------------------------------------------------------------------
// pack W (fp32 [rows][1024]) + Bmat (fp32 [rows][16]) -> Waug bf16 [rows][1088]
__global__ __launch_bounds__(256) void packw_kernel(
    const float* __restrict__ W, const float* __restrict__ Bm,
    short* __restrict__ Waug, int rows) {
  int i = blockIdx.x * 256 + threadIdx.x;
  int total = rows * 136;
  if (i >= total) return;
  int row = i / 136;
  int c8 = (i - row * 136) * 8;
  bf16x8 p;
  if (c8 < 1024) {
    float4 v0 = *(const float4*)(W + (size_t)row * 1024 + c8);
    float4 v1 = *(const float4*)(W + (size_t)row * 1024 + c8 + 4);
    p[0] = f2bf(v0.x); p[1] = f2bf(v0.y); p[2] = f2bf(v0.z); p[3] = f2bf(v0.w);
    p[4] = f2bf(v1.x); p[5] = f2bf(v1.y); p[6] = f2bf(v1.z); p[7] = f2bf(v1.w);
  } else if (c8 < 1040) {
#pragma unroll
    for (int j = 0; j < 8; j++) p[j] = f2bf(Bm[(size_t)row * 16 + (c8 - 1024) + j]);
  } else {
#pragma unroll
    for (int j = 0; j < 8; j++) p[j] = 0;
  }
  *(bf16x8*)(Waug + (size_t)row * KAUG + c8) = p;
}

// ---------------------------------------------------------------------------
// 128x128 bf16 MFMA GEMM, K = KAUG. A [M][KAUG], B [N][KAUG] (both K-major).
// EPI 0: QKV epilogue (bias, q-scale*log2e, fake-quant K/V, K->[bh][t][d],
//        V->TRANSPOSED [bh][d][t] so attention needs no in-kernel transpose)
// EPI 1: proj epilogue (bias, fp32 out)
template <int EPI>
__global__ __launch_bounds__(256) void gemm_kernel(
    const short* __restrict__ Amat, const short* __restrict__ Bmat,
    const float* __restrict__ bias,
    const float* __restrict__ kv_scale, const float* __restrict__ kv_zp,
    short* __restrict__ Qb, short* __restrict__ Kb, short* __restrict__ Vt,
    float* __restrict__ Out) {
  __shared__ short Als[128 * 64];
  __shared__ short Bls[128 * 64];
  const int tid = threadIdx.x;
  const int lane = tid & 63;
  const int wid = tid >> 6;
  const int wr = wid >> 1, wc = wid & 1;
  const int r16 = lane & 15, g = lane >> 4;
  const int bm = blockIdx.x * 128;
  const int bn = blockIdx.y * 128;

  f32x4 zero = {0.f, 0.f, 0.f, 0.f};
  f32x4 acc[4][4];
#pragma unroll
  for (int i = 0; i < 4; i++)
#pragma unroll
    for (int j = 0; j < 4; j++) acc[i][j] = zero;

  for (int k0 = 0; k0 < KAUG; k0 += 64) {
    __syncthreads();
#pragma unroll
    for (int i = 0; i < 4; i++) {
      int L = i * 256 + tid;
      int row = L >> 3, cs = L & 7;
      int cg = cs ^ (row & 7);
      gload_lds16(Amat + (size_t)(bm + row) * KAUG + k0 + cg * 8,
                  (char*)Als + (i * 256 + wid * 64) * 16);
      gload_lds16(Bmat + (size_t)(bn + row) * KAUG + k0 + cg * 8,
                  (char*)Bls + (i * 256 + wid * 64) * 16);
    }
    __syncthreads();
#pragma unroll
    for (int kk = 0; kk < 2; kk++) {
      bf16x8 a[4], b[4];
#pragma unroll
      for (int mi = 0; mi < 4; mi++) {
        int row = wr * 64 + mi * 16 + r16;
        int cs = (kk * 4 + g) ^ (row & 7);
        a[mi] = *(const bf16x8*)((const char*)Als + (row * 8 + cs) * 16);
      }
#pragma unroll
      for (int ni = 0; ni < 4; ni++) {
        int row = wc * 64 + ni * 16 + r16;
        int cs = (kk * 4 + g) ^ (row & 7);
        b[ni] = *(const bf16x8*)((const char*)Bls + (row * 8 + cs) * 16);
      }
#pragma unroll
      for (int mi = 0; mi < 4; mi++)
#pragma unroll
        for (int ni = 0; ni < 4; ni++)
          acc[mi][ni] = __builtin_amdgcn_mfma_f32_16x16x32_bf16(
              a[mi], b[ni], acc[mi][ni], 0, 0, 0);
    }
  }

  if (EPI == 0) {
    const float scale = kv_scale[0];
    const float zp = kv_zp[0];
    const int which = bn >> 10;  // 0=Q 1=K 2=V (uniform per block)
#pragma unroll
    for (int mi = 0; mi < 4; mi++)
#pragma unroll
      for (int ni = 0; ni < 4; ni++)
#pragma unroll
        for (int r = 0; r < 4; r++) {
          int m = bm + wr * 64 + mi * 16 + g * 4 + r;
          int n = bn + wc * 64 + ni * 16 + r16;
          float val = acc[mi][ni][r] + bias[n];
          int hn = n & 1023;
          int bhm = (m >> 11) * 16 + (hn >> 6);
          int t = m & 2047;
          int d = hn & 63;
          if (which == 0) {
            // fold 1/sqrt(64) and log2(e) so attn softmax uses exp2
            Qb[((size_t)bhm * TT + t) * 64 + d] =
                f2bf(val * 0.125f * 1.44269504088896340736f);
          } else {
            float q = rintf(val / scale + zp);   // round-half-even like jnp.round
            q = fminf(fmaxf(q, 0.f), 255.f);
            float deq = (q - zp) * scale;
            if (which == 1) Kb[((size_t)bhm * TT + t) * 64 + d] = f2bf(deq);
            else            Vt[((size_t)bhm * 64 + d) * TT + t] = f2bf(deq);
          }
        }
  } else {
#pragma unroll
    for (int mi = 0; mi < 4; mi++)
#pragma unroll
      for (int ni = 0; ni < 4; ni++)
#pragma unroll
        for (int r = 0; r < 4; r++) {
          int m = bm + wr * 64 + mi * 16 + g * 4 + r;
          int n = bn + wc * 64 + ni * 16 + r16;
          Out[(size_t)m * CDIM + n] = acc[mi][ni][r] + bias[n];
        }
  }
}

// ---------------------------------------------------------------------------
// Causal flash attention, swapped-operand 32x32x16 MFMA structure (guide §B).
// Block = 4 warps x 32 q rows (QBLK=128), KVBLK=64.
// S^T = mfma(K, Q): lane owns full P row for q = lane&31 -> in-register
// softmax (1 shfl per reduce). O^T = mfma(V^T, P^T): softmax state stays
// lane-uniform. P^T fragments built via v_cvt_pk_bf16_f32 + permlane32_swap.
// K and V^T staged by global_load_lds (linear dest, inverse-swizzled source,
// XOR-swizzled ds_read_b128).
__global__ __launch_bounds__(256) void attn_kernel(
    const short* __restrict__ Qb, const short* __restrict__ Kb,
    const short* __restrict__ Vt, short* __restrict__ Caug) {
  __shared__ short Kls[64 * 64];   // [kv][d] 8KB, chunk-swizzled
  __shared__ short Vls[64 * 64];   // [d][kv] 8KB, chunk-swizzled
  const int tid = threadIdx.x;
  const int lane = tid & 63;
  const int w = tid >> 6;
  const int q32 = lane & 31;
  const int hi = lane >> 5;
  const int bh = blockIdx.y;
  const int qb = 15 - blockIdx.x;     // biggest blocks first
  const int q0 = qb * 128;
  const int q0w = q0 + w * 32;
  const size_t kvbase = (size_t)bh * TT * 64;
  const int swz = q32 & 7;

  // Q fragments (B-operand: col=q=lane&31, k = d = kd*16 + hi*8 + j)
  bf16x8 qf[4];
  {
    const short* qp = Qb + kvbase + (size_t)(q0w + q32) * 64;
#pragma unroll
    for (int kd = 0; kd < 4; kd++)
      qf[kd] = *(const bf16x8*)(qp + kd * 16 + hi * 8);
  }
  f32x16 accT[2];
#pragma unroll
  for (int i = 0; i < 16; i++) { accT[0][i] = 0.f; accT[1][i] = 0.f; }
  float m_run = -1e30f, l_run = 0.f;

  const int nt = (q0 + 128) >> 6;
  for (int kt = 0; kt < nt; kt++) {
    const int kv0 = kt * 64;
    __syncthreads();
    // stage K [64 kv][64 d] and Vt [64 d][64 kv]; LDS chunk (row,c) holds
    // global chunk (row, c ^ (row&7))
#pragma unroll
    for (int p = 0; p < 2; p++) {
      int L = p * 256 + tid;
      int row = L >> 3;
      int cg = (L & 7) ^ (row & 7);
      gload_lds16(Kb + kvbase + (size_t)(kv0 + row) * 64 + cg * 8,
                  (char*)Kls + (p * 256 + w * 64) * 16);
      gload_lds16(Vt + kvbase + (size_t)row * TT + kv0 + cg * 8,
                  (char*)Vls + (p * 256 + w * 64) * 16);
    }
    __syncthreads();
    if (kv0 > q0w + 31) continue;   // fully-masked tile for this warp

    // S^T = K @ Q^T : D[row=kv][col=q]; lane: col q32, rows crow(r,hi)
    f32x16 sA, sB;
#pragma unroll
    for (int i = 0; i < 16; i++) { sA[i] = 0.f; sB[i] = 0.f; }
#pragma unroll
    for (int kd = 0; kd < 4; kd++) {
      int coff = ((kd * 2 + hi) ^ swz) * 16;
      bf16x8 a0 = *(const bf16x8*)((const char*)Kls + q32 * 128 + coff);
      bf16x8 a1 = *(const bf16x8*)((const char*)Kls + (32 + q32) * 128 + coff);
      sA = __builtin_amdgcn_mfma_f32_32x32x16_bf16(a0, qf[kd], sA, 0, 0, 0);
      sB = __builtin_amdgcn_mfma_f32_32x32x16_bf16(a1, qf[kd], sB, 0, 0, 0);
    }
    const int qg = q0w + q32;
    if (kv0 + 63 > q0w) {   // causal mask needed
#pragma unroll
      for (int r = 0; r < 16; r++) {
        int kvr = kv0 + (r & 3) + 8 * (r >> 2) + 4 * hi;
        if (kvr > qg) sA[r] = -1e30f;
        if (kvr + 32 > qg) sB[r] = -1e30f;
      }
    }
    // in-register online softmax (base-2 domain; log2e folded into Q)
    float mx = sA[0];
#pragma unroll
    for (int r = 1; r < 16; r++) mx = fmaxf(mx, sA[r]);
#pragma unroll
    for (int r = 0; r < 16; r++) mx = fmaxf(mx, sB[r]);
    mx = fmaxf(mx, __shfl_xor(mx, 32));
    float mnew = fmaxf(m_run, mx);
    float corr = exp2f(m_run - mnew);
    float rs = 0.f;
#pragma unroll
    for (int r = 0; r < 16; r++) {
      sA[r] = exp2f(sA[r] - mnew);
      sB[r] = exp2f(sB[r] - mnew);
      rs += sA[r] + sB[r];
    }
    rs += __shfl_xor(rs, 32);
    l_run = l_run * corr + rs;
    m_run = mnew;
#pragma unroll
    for (int r = 0; r < 16; r++) { accT[0][r] *= corr; accT[1][r] *= corr; }

    // Build P^T B-fragments: lane needs P[q=lane&31][ks*16 + hi*8 + j].
    // Lane (hi=0) holds kv classes {0-3 mod 8}, partner lane^32 holds {4-7}.
    // permlane32_swap(wlo,whi): wlo -> {own lo | partner hi}, whi -> vice versa.
    bf16x8 pf[4];
#pragma unroll
    for (int t2 = 0; t2 < 2; t2++) {
#pragma unroll
      for (int s01 = 0; s01 < 2; s01++) {
        int base = 8 * s01;
        unsigned int wlo0, wlo1, whi0, whi1;
        if (t2 == 0) {
          wlo0 = cvt_pk_bf16(sA[base + 0], sA[base + 1]);
          wlo1 = cvt_pk_bf16(sA[base + 2], sA[base + 3]);
          whi0 = cvt_pk_bf16(sA[base + 4], sA[base + 5]);
          whi1 = cvt_pk_bf16(sA[base + 6], sA[base + 7]);
        } else {
          wlo0 = cvt_pk_bf16(sB[base + 0], sB[base + 1]);
          wlo1 = cvt_pk_bf16(sB[base + 2], sB[base + 3]);
          whi0 = cvt_pk_bf16(sB[base + 4], sB[base + 5]);
          whi1 = cvt_pk_bf16(sB[base + 6], sB[base + 7]);
        }
        asm volatile("v_permlane32_swap_b32 %0, %1" : "+v"(wlo0), "+v"(whi0));
        asm volatile("v_permlane32_swap_b32 %0, %1" : "+v"(wlo1), "+v"(whi1));
        union { unsigned int u[4]; bf16x8 v; } cc;
        cc.u[0] = wlo0; cc.u[1] = wlo1; cc.u[2] = whi0; cc.u[3] = whi1;
        pf[t2 * 2 + s01] = cc.v;
      }
    }
    // O^T += V^T @ P^T : D[row=d][col=q]
#pragma unroll
    for (int db = 0; db < 2; db++) {
      const int row = db * 32 + q32;
#pragma unroll
      for (int ks = 0; ks < 4; ks++) {
        bf16x8 vf = *(const bf16x8*)((const char*)Vls + row * 128 +
                                     (((ks * 2 + hi) ^ swz) * 16));
        accT[db] = __builtin_amdgcn_mfma_f32_32x32x16_bf16(vf, pf[ks],
                                                           accT[db], 0, 0, 0);
      }
    }
  }

  // epilogue: O^T[d = db*32 + crow(r,hi)][q = q32] / l -> Caug[(b,q)][h*64+d]
  const float rinv = 1.f / l_run;
  const int b = bh >> 4, h = bh & 15;
  short* cp = Caug + (size_t)(b * TT + q0w + q32) * KAUG + h * 64;
#pragma unroll
  for (int db = 0; db < 2; db++)
#pragma unroll
    for (int rg = 0; rg < 4; rg++) {
      short4v pk4;
#pragma unroll
      for (int rr = 0; rr < 4; rr++)
        pk4[rr] = f2bf(accT[db][rg * 4 + rr] * rinv);
      *(short4v*)(cp + db * 32 + rg * 8 + hi * 4) = pk4;
    }
}

// ---------------------------------------------------------------------------
extern "C" void kernel_launch(void* const* d_in, const int* in_sizes, int n_in,
                              void* d_out, int out_size, void* d_ws, size_t ws_size,
                              hipStream_t stream) {
  const float* x       = (const float*)d_in[0];
  const float* W_attn  = (const float*)d_in[1];
  const float* b_attn  = (const float*)d_in[2];
  const float* A_attn  = (const float*)d_in[3];
  const float* B_attn  = (const float*)d_in[4];
  const float* W_proj  = (const float*)d_in[5];
  const float* b_proj  = (const float*)d_in[6];
  const float* A_proj  = (const float*)d_in[7];
  const float* B_proj  = (const float*)d_in[8];
  const float* kv_scale = (const float*)d_in[9];
  const float* kv_zp    = (const float*)d_in[10];
  float* out = (float*)d_out;

  char* p = (char*)d_ws;
  short* Xaug  = (short*)p; p += (size_t)BT * KAUG * 2;
  short* Waug1 = (short*)p; p += (size_t)3072 * KAUG * 2;
  short* Waug2 = (short*)p; p += (size_t)1024 * KAUG * 2;
  short* Caug  = (short*)p; p += (size_t)BT * KAUG * 2;
  short* Qb    = (short*)p; p += (size_t)32 * TT * 64 * 2;
  short* Kb    = (short*)p; p += (size_t)32 * TT * 64 * 2;
  short* Vt    = (short*)p; p += (size_t)32 * TT * 64 * 2;

  rank1_kernel<<<dim3(256), dim3(256), 0, stream>>>(x, A_attn, Xaug);
  packw_kernel<<<dim3(1632), dim3(256), 0, stream>>>(W_attn, B_attn, Waug1, 3072);
  packw_kernel<<<dim3(544), dim3(256), 0, stream>>>(W_proj, B_proj, Waug2, 1024);
  gemm_kernel<0><<<dim3(32, 24), dim3(256), 0, stream>>>(
      Xaug, Waug1, b_attn, kv_scale, kv_zp, Qb, Kb, Vt, (float*)nullptr);
  attn_kernel<<<dim3(16, 32), dim3(256), 0, stream>>>(Qb, Kb, Vt, Caug);
  rank2_kernel<<<dim3(256), dim3(256), 0, stream>>>(A_proj, Caug);
  gemm_kernel<1><<<dim3(32, 8), dim3(256), 0, stream>>>(
      Caug, Waug2, b_proj, kv_scale, kv_zp,
      (short*)nullptr, (short*)nullptr, (short*)nullptr, out);
}

// Round 3
// 204.310 us; speedup vs baseline: 1.7841x; 1.1367x over previous
//
#include <hip/hip_runtime.h>
#include <math.h>

#define TT 2048
#define CDIM 1024
#define KAUG 1088
#define BT 4096

typedef __attribute__((ext_vector_type(8))) short bf16x8;
typedef __attribute__((ext_vector_type(4))) short short4v;
typedef __attribute__((ext_vector_type(4))) float f32x4;
typedef __attribute__((ext_vector_type(16))) float f32x16;

static __device__ __forceinline__ float bf2f(short s) {
  union { unsigned int u; float f; } c;
  c.u = ((unsigned int)(unsigned short)s) << 16;
  return c.f;
}
static __device__ __forceinline__ short f2bf(float f) {
  union { float f; unsigned int u; } c; c.f = f;
  unsigned int u = c.u;
  u += 0x7fff + ((u >> 16) & 1);   // round-to-nearest-even
  return (short)(u >> 16);
}

static __device__ __forceinline__ void gload_lds16(const void* g, void* l) {
  __builtin_amdgcn_global_load_lds(
      (const __attribute__((address_space(1))) void*)g,
      (__attribute__((address_space(3))) void*)l, 16, 0, 0);
}

static __device__ __forceinline__ unsigned int cvt_pk_bf16(float lo, float hi) {
  unsigned int r;
  asm("v_cvt_pk_bf16_f32 %0, %1, %2" : "=v"(r) : "v"(lo), "v"(hi));
  return r;
}

// ---------------------------------------------------------------------------
// rank1: xa = x @ A_attn^T (fp32), fused with packing x -> Xaug (bf16) and
// writing cols [1024,1040) = 2*xa (bf16), [1040,1088) = 0.
__global__ __launch_bounds__(256) void rank1_kernel(
    const float* __restrict__ x, const float* __restrict__ Aattn,
    short* __restrict__ Xaug) {
  __shared__ float xls[16][1024];
  const int tid = threadIdx.x;
  const int row0 = blockIdx.x * 16;
  for (int i = tid; i < 16 * 256; i += 256) {
    int row = i >> 8, c4 = (i & 255) * 4;
    float4 v = *(const float4*)(x + (size_t)(row0 + row) * CDIM + c4);
    *(float4*)&xls[row][c4] = v;
    short4v p;
    p.x = f2bf(v.x); p.y = f2bf(v.y); p.z = f2bf(v.z); p.w = f2bf(v.w);
    *(short4v*)(Xaug + (size_t)(row0 + row) * KAUG + c4) = p;
  }
  __syncthreads();
  const int row = tid >> 4, r = tid & 15;
  float acc = 0.f;
  for (int c = 0; c < 1024; c += 4) {
    float4 a = *(const float4*)(Aattn + (size_t)r * 1024 + c);
    float4 xv = *(const float4*)&xls[row][c];
    acc += a.x * xv.x + a.y * xv.y + a.z * xv.z + a.w * xv.w;
  }
  Xaug[(size_t)(row0 + row) * KAUG + 1024 + r] = f2bf(2.f * acc);
  for (int i = tid; i < 16 * 48; i += 256) {
    int rr = i / 48, cc = 1040 + (i % 48);
    Xaug[(size_t)(row0 + rr) * KAUG + cc] = 0;
  }
}

// ---------------------------------------------------------------------------
// rank2: ca = ctx @ A_proj^T, ctx = Caug cols [0,1024) (bf16, stride KAUG);
// writes Caug cols [1024,1040) = 2*ca (bf16), [1040,1088) = 0.
__global__ __launch_bounds__(256) void rank2_kernel(
    const float* __restrict__ Aproj, short* __restrict__ Caug) {
  __shared__ float cls[16][1024];
  const int tid = threadIdx.x;
  const int row0 = blockIdx.x * 16;
  for (int i = tid; i < 16 * 128; i += 256) {
    int row = i >> 7, c8 = (i & 127) * 8;
    bf16x8 v = *(const bf16x8*)(Caug + (size_t)(row0 + row) * KAUG + c8);
#pragma unroll
    for (int j = 0; j < 8; j++) cls[row][c8 + j] = bf2f(v[j]);
  }
  __syncthreads();
  const int row = tid >> 4, r = tid & 15;
  float acc = 0.f;
  for (int c = 0; c < 1024; c += 4) {
    float4 a = *(const float4*)(Aproj + (size_t)r * 1024 + c);
    float4 xv = *(const float4*)&cls[row][c];
    acc += a.x * xv.x + a.y * xv.y + a.z * xv.z + a.w * xv.w;
  }
  Caug[(size_t)(row0 + row) * KAUG + 1024 + r] = f2bf(2.f * acc);
  for (int i = tid; i < 16 * 48; i += 256) {
    int rr = i / 48, cc = 1040 + (i % 48);
    Caug[(size_t)(row0 + rr) * KAUG + cc] = 0;
  }
}

// ---------------------------------------------------------------------------
// pack W (fp32 [rows][1024]) + Bmat (fp32 [rows][16]) -> Waug bf16 [rows][1088]
__global__ __launch_bounds__(256) void packw_kernel(
    const float* __restrict__ W, const float* __restrict__ Bm,
    short* __restrict__ Waug, int rows) {
  int i = blockIdx.x * 256 + threadIdx.x;
  int total = rows * 136;
  if (i >= total) return;
  int row = i / 136;
  int c8 = (i - row * 136) * 8;
  bf16x8 p;
  if (c8 < 1024) {
    float4 v0 = *(const float4*)(W + (size_t)row * 1024 + c8);
    float4 v1 = *(const float4*)(W + (size_t)row * 1024 + c8 + 4);
    p[0] = f2bf(v0.x); p[1] = f2bf(v0.y); p[2] = f2bf(v0.z); p[3] = f2bf(v0.w);
    p[4] = f2bf(v1.x); p[5] = f2bf(v1.y); p[6] = f2bf(v1.z); p[7] = f2bf(v1.w);
  } else if (c8 < 1040) {
#pragma unroll
    for (int j = 0; j < 8; j++) p[j] = f2bf(Bm[(size_t)row * 16 + (c8 - 1024) + j]);
  } else {
#pragma unroll
    for (int j = 0; j < 8; j++) p[j] = 0;
  }
  *(bf16x8*)(Waug + (size_t)row * KAUG + c8) = p;
}

// ---------------------------------------------------------------------------
// 128x128 bf16 MFMA GEMM, K = KAUG. A [M][KAUG], B [N][KAUG] (both K-major).
// EPI 0: QKV epilogue; EPI 1: proj epilogue (bias, fp32 out)
template <int EPI>
__global__ __launch_bounds__(256) void gemm_kernel(
    const short* __restrict__ Amat, const short* __restrict__ Bmat,
    const float* __restrict__ bias,
    const float* __restrict__ kv_scale, const float* __restrict__ kv_zp,
    short* __restrict__ Qb, short* __restrict__ Kb, short* __restrict__ Vt,
    float* __restrict__ Out) {
  __shared__ short Als[128 * 64];
  __shared__ short Bls[128 * 64];
  const int tid = threadIdx.x;
  const int lane = tid & 63;
  const int wid = tid >> 6;
  const int wr = wid >> 1, wc = wid & 1;
  const int r16 = lane & 15, g = lane >> 4;
  const int bm = blockIdx.x * 128;
  const int bn = blockIdx.y * 128;

  f32x4 zero = {0.f, 0.f, 0.f, 0.f};
  f32x4 acc[4][4];
#pragma unroll
  for (int i = 0; i < 4; i++)
#pragma unroll
    for (int j = 0; j < 4; j++) acc[i][j] = zero;

  for (int k0 = 0; k0 < KAUG; k0 += 64) {
    __syncthreads();
#pragma unroll
    for (int i = 0; i < 4; i++) {
      int L = i * 256 + tid;
      int row = L >> 3, cs = L & 7;
      int cg = cs ^ (row & 7);
      gload_lds16(Amat + (size_t)(bm + row) * KAUG + k0 + cg * 8,
                  (char*)Als + (i * 256 + wid * 64) * 16);
      gload_lds16(Bmat + (size_t)(bn + row) * KAUG + k0 + cg * 8,
                  (char*)Bls + (i * 256 + wid * 64) * 16);
    }
    __syncthreads();
#pragma unroll
    for (int kk = 0; kk < 2; kk++) {
      bf16x8 a[4], b[4];
#pragma unroll
      for (int mi = 0; mi < 4; mi++) {
        int row = wr * 64 + mi * 16 + r16;
        int cs = (kk * 4 + g) ^ (row & 7);
        a[mi] = *(const bf16x8*)((const char*)Als + (row * 8 + cs) * 16);
      }
#pragma unroll
      for (int ni = 0; ni < 4; ni++) {
        int row = wc * 64 + ni * 16 + r16;
        int cs = (kk * 4 + g) ^ (row & 7);
        b[ni] = *(const bf16x8*)((const char*)Bls + (row * 8 + cs) * 16);
      }
#pragma unroll
      for (int mi = 0; mi < 4; mi++)
#pragma unroll
        for (int ni = 0; ni < 4; ni++)
          acc[mi][ni] = __builtin_amdgcn_mfma_f32_16x16x32_bf16(
              a[mi], b[ni], acc[mi][ni], 0, 0, 0);
    }
  }

  if (EPI == 0) {
    const float scale = kv_scale[0];
    const float zp = kv_zp[0];
    const int which = bn >> 10;  // 0=Q 1=K 2=V (uniform per block)
#pragma unroll
    for (int mi = 0; mi < 4; mi++)
#pragma unroll
      for (int ni = 0; ni < 4; ni++)
#pragma unroll
        for (int r = 0; r < 4; r++) {
          int m = bm + wr * 64 + mi * 16 + g * 4 + r;
          int n = bn + wc * 64 + ni * 16 + r16;
          float val = acc[mi][ni][r] + bias[n];
          int hn = n & 1023;
          int bhm = (m >> 11) * 16 + (hn >> 6);
          int t = m & 2047;
          int d = hn & 63;
          if (which == 0) {
            // fold 1/sqrt(64) and log2(e) so attn softmax uses exp2
            Qb[((size_t)bhm * TT + t) * 64 + d] =
                f2bf(val * 0.125f * 1.44269504088896340736f);
          } else {
            float q = rintf(val / scale + zp);   // round-half-even like jnp.round
            q = fminf(fmaxf(q, 0.f), 255.f);
            float deq = (q - zp) * scale;
            if (which == 1) Kb[((size_t)bhm * TT + t) * 64 + d] = f2bf(deq);
            else            Vt[((size_t)bhm * 64 + d) * TT + t] = f2bf(deq);
          }
        }
  } else {
#pragma unroll
    for (int mi = 0; mi < 4; mi++)
#pragma unroll
      for (int ni = 0; ni < 4; ni++)
#pragma unroll
        for (int r = 0; r < 4; r++) {
          int m = bm + wr * 64 + mi * 16 + g * 4 + r;
          int n = bn + wc * 64 + ni * 16 + r16;
          Out[(size_t)m * CDIM + n] = acc[mi][ni][r] + bias[n];
        }
  }
}

// ---------------------------------------------------------------------------
// Causal flash attention, swapped-operand 32x32x16 MFMA (guide §B), balanced
// q-block pairing + even/odd KV-tile warp split + 2-phase dbuf pipeline.
//   grid (8, B*H); 8 warps. Warp (qsub=w&3, p=w>>2): q rows q0+qsub*32..+31,
//   KV tiles of parity p. Block processes q-blocks {15-bx, bx} (34 tiles tot).
//   Per pair-step s: stage tiles {2s+2, 2s+3} into buffer pair (s+1)&1 while
//   parities compute tiles {2s, 2s+1} from pair s&1; one vmcnt(0)+s_barrier
//   per step (T3 minimum 2-phase; loads land under compute).
//   Per-segment (m,l,O^T) partials merged across parities through LDS.
__global__ __launch_bounds__(512) void attn_kernel(
    const short* __restrict__ Qb, const short* __restrict__ Kb,
    const short* __restrict__ Vt, short* __restrict__ Caug) {
  __shared__ short Kls[4 * 4096];   // 4 bufs x [64 kv][64 d], 32KB, chunk-swizzled
  __shared__ short Vls[4 * 4096];   // 4 bufs x [64 d][64 kv], 32KB, chunk-swizzled
  const int tid = threadIdx.x;
  const int lane = tid & 63;
  const int w = tid >> 6;
  const int qsub = w & 3;
  const int p = w >> 2;
  const int q32 = lane & 31;
  const int hi = lane >> 5;
  const int bx = blockIdx.x;
  const int bh = blockIdx.y;
  const size_t kvbase = (size_t)bh * TT * 64;
  const int swz = q32 & 7;
  const int b = bh >> 4, h = bh & 15;

  // staging geometry (per thread, constant): thread stages one 16B chunk of
  // each tile; LDS chunk (row, c) holds global chunk (row, c ^ (row&7)).
  const int srow = tid >> 3;
  const int scg = (tid & 7) ^ (srow & 7);
  const int sdst = w * 1024;  // byte offset of this wave's 1KB within a buffer

  for (int seg = 0; seg < 2; seg++) {
    const int qb = seg ? bx : 15 - bx;   // pair (15-bx, bx): 34 tiles total
    const int q0 = qb * 128;
    const int q0w = q0 + qsub * 32;
    const int nt = 2 * qb + 2;
    const int ns = nt >> 1;

    bf16x8 qf[4];
    {
      const short* qp = Qb + kvbase + (size_t)(q0w + q32) * 64;
#pragma unroll
      for (int kd = 0; kd < 4; kd++)
        qf[kd] = *(const bf16x8*)(qp + kd * 16 + hi * 8);
    }
    f32x16 accT[2];
#pragma unroll
    for (int i = 0; i < 16; i++) { accT[0][i] = 0.f; accT[1][i] = 0.f; }
    float m_run = -1e30f, l_run = 0.f;

    // prologue: stage pair 0 into buffers {0,1}
#pragma unroll
    for (int t2 = 0; t2 < 2; t2++) {
      int kv0 = t2 * 64;
      gload_lds16(Kb + kvbase + (size_t)(kv0 + srow) * 64 + scg * 8,
                  (char*)Kls + t2 * 8192 + sdst);
      gload_lds16(Vt + kvbase + (size_t)srow * TT + kv0 + scg * 8,
                  (char*)Vls + t2 * 8192 + sdst);
    }
    asm volatile("s_waitcnt vmcnt(0)" ::: "memory");
    __builtin_amdgcn_s_barrier();
    __builtin_amdgcn_sched_barrier(0);

    for (int s = 0; s < ns; s++) {
      if (s + 1 < ns) {
        const int bp = ((s + 1) & 1) * 2;
#pragma unroll
        for (int t2 = 0; t2 < 2; t2++) {
          int kv0 = (2 * (s + 1) + t2) * 64;
          gload_lds16(Kb + kvbase + (size_t)(kv0 + srow) * 64 + scg * 8,
                      (char*)Kls + (bp + t2) * 8192 + sdst);
          gload_lds16(Vt + kvbase + (size_t)srow * TT + kv0 + scg * 8,
                      (char*)Vls + (bp + t2) * 8192 + sdst);
        }
      }
      const int kv0 = (2 * s + p) * 64;
      if (kv0 <= q0w + 31) {   // warp-uniform causal skip
        const char* Kbase = (const char*)Kls + (2 * (s & 1) + p) * 8192;
        const char* Vbase = (const char*)Vls + (2 * (s & 1) + p) * 8192;
        // S^T = K @ Q^T
        f32x16 sA, sB;
#pragma unroll
        for (int i = 0; i < 16; i++) { sA[i] = 0.f; sB[i] = 0.f; }
        __builtin_amdgcn_s_setprio(1);
#pragma unroll
        for (int kd = 0; kd < 4; kd++) {
          int coff = ((kd * 2 + hi) ^ swz) * 16;
          bf16x8 a0 = *(const bf16x8*)(Kbase + q32 * 128 + coff);
          bf16x8 a1 = *(const bf16x8*)(Kbase + (32 + q32) * 128 + coff);
          sA = __builtin_amdgcn_mfma_f32_32x32x16_bf16(a0, qf[kd], sA, 0, 0, 0);
          sB = __builtin_amdgcn_mfma_f32_32x32x16_bf16(a1, qf[kd], sB, 0, 0, 0);
        }
        __builtin_amdgcn_s_setprio(0);
        const int qg = q0w + q32;
        if (kv0 + 63 > q0w) {   // causal mask needed
#pragma unroll
          for (int r = 0; r < 16; r++) {
            int kvr = kv0 + (r & 3) + 8 * (r >> 2) + 4 * hi;
            if (kvr > qg) sA[r] = -1e30f;
            if (kvr + 32 > qg) sB[r] = -1e30f;
          }
        }
        // in-register online softmax (base-2; log2e folded into Q)
        float mx = sA[0];
#pragma unroll
        for (int r = 1; r < 16; r++) mx = fmaxf(mx, sA[r]);
#pragma unroll
        for (int r = 0; r < 16; r++) mx = fmaxf(mx, sB[r]);
        mx = fmaxf(mx, __shfl_xor(mx, 32));
        float mnew = fmaxf(m_run, mx);
        float corr = exp2f(m_run - mnew);
        float rs = 0.f;
#pragma unroll
        for (int r = 0; r < 16; r++) {
          sA[r] = exp2f(sA[r] - mnew);
          sB[r] = exp2f(sB[r] - mnew);
          rs += sA[r] + sB[r];
        }
        rs += __shfl_xor(rs, 32);
        l_run = l_run * corr + rs;
        m_run = mnew;
#pragma unroll
        for (int r = 0; r < 16; r++) { accT[0][r] *= corr; accT[1][r] *= corr; }

        // P^T B-fragments via cvt_pk + permlane32_swap (T12)
        bf16x8 pf[4];
#pragma unroll
        for (int t2 = 0; t2 < 2; t2++) {
#pragma unroll
          for (int s01 = 0; s01 < 2; s01++) {
            int base = 8 * s01;
            unsigned int wlo0, wlo1, whi0, whi1;
            if (t2 == 0) {
              wlo0 = cvt_pk_bf16(sA[base + 0], sA[base + 1]);
              wlo1 = cvt_pk_bf16(sA[base + 2], sA[base + 3]);
              whi0 = cvt_pk_bf16(sA[base + 4], sA[base + 5]);
              whi1 = cvt_pk_bf16(sA[base + 6], sA[base + 7]);
            } else {
              wlo0 = cvt_pk_bf16(sB[base + 0], sB[base + 1]);
              wlo1 = cvt_pk_bf16(sB[base + 2], sB[base + 3]);
              whi0 = cvt_pk_bf16(sB[base + 4], sB[base + 5]);
              whi1 = cvt_pk_bf16(sB[base + 6], sB[base + 7]);
            }
            asm volatile("v_permlane32_swap_b32 %0, %1" : "+v"(wlo0), "+v"(whi0));
            asm volatile("v_permlane32_swap_b32 %0, %1" : "+v"(wlo1), "+v"(whi1));
            union { unsigned int u[4]; bf16x8 v; } cc;
            cc.u[0] = wlo0; cc.u[1] = wlo1; cc.u[2] = whi0; cc.u[3] = whi1;
            pf[t2 * 2 + s01] = cc.v;
          }
        }
        // O^T += V^T @ P^T
        __builtin_amdgcn_s_setprio(1);
#pragma unroll
        for (int db = 0; db < 2; db++) {
          const int row = db * 32 + q32;
#pragma unroll
          for (int ks = 0; ks < 4; ks++) {
            bf16x8 vf = *(const bf16x8*)(Vbase + row * 128 +
                                         (((ks * 2 + hi) ^ swz) * 16));
            accT[db] = __builtin_amdgcn_mfma_f32_32x32x16_bf16(vf, pf[ks],
                                                               accT[db], 0, 0, 0);
          }
        }
        __builtin_amdgcn_s_setprio(0);
      }
      asm volatile("s_waitcnt vmcnt(0) lgkmcnt(0)" ::: "memory");
      __builtin_amdgcn_s_barrier();
      __builtin_amdgcn_sched_barrier(0);
    }

    // merge parity partials through LDS (reuse K/V buffers as scratch)
    float* scrO = (float*)Kls;    // [qsub][32 rows][64 lanes] f32 = 32KB
    float* scrML = (float*)Vls;   // m: [qsub*64+lane], l: 256 + same
    if (p == 1) {
#pragma unroll
      for (int db = 0; db < 2; db++)
#pragma unroll
        for (int r = 0; r < 16; r++)
          scrO[qsub * 2048 + (db * 16 + r) * 64 + lane] = accT[db][r];
      scrML[qsub * 64 + lane] = m_run;
      scrML[256 + qsub * 64 + lane] = l_run;
    }
    __syncthreads();
    if (p == 0) {
      float m_o = scrML[qsub * 64 + lane];
      float l_o = scrML[256 + qsub * 64 + lane];
      float mm = fmaxf(m_run, m_o);
      float ce = exp2f(m_run - mm), co = exp2f(m_o - mm);
      float lt = l_run * ce + l_o * co;
      float rinv = 1.f / lt;
      short* cp = Caug + (size_t)(b * TT + q0w + q32) * KAUG + h * 64;
#pragma unroll
      for (int db = 0; db < 2; db++)
#pragma unroll
        for (int rg = 0; rg < 4; rg++) {
          short4v pk4;
#pragma unroll
          for (int rr = 0; rr < 4; rr++) {
            int r = rg * 4 + rr;
            float v = accT[db][r] * ce +
                      scrO[qsub * 2048 + (db * 16 + r) * 64 + lane] * co;
            pk4[rr] = f2bf(v * rinv);
          }
          *(short4v*)(cp + db * 32 + rg * 8 + hi * 4) = pk4;
        }
    }
    __syncthreads();
  }
}

// ---------------------------------------------------------------------------
extern "C" void kernel_launch(void* const* d_in, const int* in_sizes, int n_in,
                              void* d_out, int out_size, void* d_ws, size_t ws_size,
                              hipStream_t stream) {
  const float* x       = (const float*)d_in[0];
  const float* W_attn  = (const float*)d_in[1];
  const float* b_attn  = (const float*)d_in[2];
  const float* A_attn  = (const float*)d_in[3];
  const float* B_attn  = (const float*)d_in[4];
  const float* W_proj  = (const float*)d_in[5];
  const float* b_proj  = (const float*)d_in[6];
  const float* A_proj  = (const float*)d_in[7];
  const float* B_proj  = (const float*)d_in[8];
  const float* kv_scale = (const float*)d_in[9];
  const float* kv_zp    = (const float*)d_in[10];
  float* out = (float*)d_out;

  char* p = (char*)d_ws;
  short* Xaug  = (short*)p; p += (size_t)BT * KAUG * 2;
  short* Waug1 = (short*)p; p += (size_t)3072 * KAUG * 2;
  short* Waug2 = (short*)p; p += (size_t)1024 * KAUG * 2;
  short* Caug  = (short*)p; p += (size_t)BT * KAUG * 2;
  short* Qb    = (short*)p; p += (size_t)32 * TT * 64 * 2;
  short* Kb    = (short*)p; p += (size_t)32 * TT * 64 * 2;
  short* Vt    = (short*)p; p += (size_t)32 * TT * 64 * 2;

  rank1_kernel<<<dim3(256), dim3(256), 0, stream>>>(x, A_attn, Xaug);
  packw_kernel<<<dim3(1632), dim3(256), 0, stream>>>(W_attn, B_attn, Waug1, 3072);
  packw_kernel<<<dim3(544), dim3(256), 0, stream>>>(W_proj, B_proj, Waug2, 1024);
  gemm_kernel<0><<<dim3(32, 24), dim3(256), 0, stream>>>(
      Xaug, Waug1, b_attn, kv_scale, kv_zp, Qb, Kb, Vt, (float*)nullptr);
  attn_kernel<<<dim3(8, 32), dim3(512), 0, stream>>>(Qb, Kb, Vt, Caug);
  rank2_kernel<<<dim3(256), dim3(256), 0, stream>>>(A_proj, Caug);
  gemm_kernel<1><<<dim3(32, 8), dim3(256), 0, stream>>>(
      Caug, Waug2, b_proj, kv_scale, kv_zp,
      (short*)nullptr, (short*)nullptr, (short*)nullptr, out);
}